// Round 2
// baseline (248.268 us; speedup 1.0000x reference)
//
#include <hip/hip_runtime.h>

// Problem constants (fixed by the reference's setup_inputs)
#define NPEND  128
#define LATENT 256
#define KCOLS  6
#define D0_C   1.0f

// One block per chain. Phase 1: r = y_chain @ K[:, :3] into LDS.
// Phase 2: chain stencil (c_i * rn_i difference) + rank-3 expansion to output.
// All storage fp32 per the reference dtypes.
__global__ __launch_bounds__(256)
void pend_kernel_f32(const float* __restrict__ y,
                     const float* __restrict__ K,
                     float* __restrict__ out)
{
    __shared__ float sR[NPEND][3];

    const int tid  = threadIdx.x;
    const int wave = tid >> 6;          // 0..3
    const int lane = tid & 63;
    const int hw   = lane >> 5;         // which row of the wave's pair
    const int hl   = lane & 31;         // lane within half-wave

    // This lane owns latent indices l = hl*8 + e (e = 0..7)
    float k0[8], k1[8], k2[8];
#pragma unroll
    for (int e = 0; e < 8; ++e) {
        const int l = hl * 8 + e;
        k0[e] = K[l * KCOLS + 0];
        k1[e] = K[l * KCOLS + 1];
        k2[e] = K[l * KCOLS + 2];
    }

    const size_t ybase = (size_t)blockIdx.x * ((size_t)NPEND * LATENT);

    // ---- Phase 1: r[p] = y[p,:] @ K[:,0:3] (fp32) ----
    for (int p = wave * 2; p < NPEND; p += 8) {
        const int row = p + hw;
        const float* yr = y + ybase + (size_t)row * LATENT + hl * 8;
        const float4 va = *(const float4*)(yr);
        const float4 vb = *(const float4*)(yr + 4);

        float s0 = va.x*k0[0] + va.y*k0[1] + va.z*k0[2] + va.w*k0[3]
                 + vb.x*k0[4] + vb.y*k0[5] + vb.z*k0[6] + vb.w*k0[7];
        float s1 = va.x*k1[0] + va.y*k1[1] + va.z*k1[2] + va.w*k1[3]
                 + vb.x*k1[4] + vb.y*k1[5] + vb.z*k1[6] + vb.w*k1[7];
        float s2 = va.x*k2[0] + va.y*k2[1] + va.z*k2[2] + va.w*k2[3]
                 + vb.x*k2[4] + vb.y*k2[5] + vb.z*k2[6] + vb.w*k2[7];

#pragma unroll
        for (int off = 16; off > 0; off >>= 1) {
            s0 += __shfl_down(s0, off, 32);
            s1 += __shfl_down(s1, off, 32);
            s2 += __shfl_down(s2, off, 32);
        }
        if (hl == 0) {
            sR[row][0] = s0; sR[row][1] = s1; sR[row][2] = s2;
        }
    }
    __syncthreads();

    // ---- Phase 2: out3[p] = t(p) - t(p+1); lam_y[p,l] = sum_d out3[d]*K[l,d] ----
    for (int p = wave * 2; p < NPEND; p += 8) {
        const int row = p + hw;

        const float rx = sR[row][0], ry = sR[row][1], rz = sR[row][2];
        float px = 0.f, py = 0.f, pz = 0.f;
        if (row > 0) { px = sR[row-1][0]; py = sR[row-1][1]; pz = sR[row-1][2]; }

        const float dx = rx - px, dy = ry - py, dz = rz - pz;
        const float n  = sqrtf(dx*dx + dy*dy + dz*dz);
        const float s  = (n - D0_C) / n;
        float ox = s * dx, oy = s * dy, oz = s * dz;

        if (row < NPEND - 1) {
            const float nx = sR[row+1][0], ny = sR[row+1][1], nz = sR[row+1][2];
            const float ex = nx - rx, ey = ny - ry, ez = nz - rz;
            const float n2 = sqrtf(ex*ex + ey*ey + ez*ez);
            const float t2 = (n2 - D0_C) / n2;
            ox -= t2 * ex; oy -= t2 * ey; oz -= t2 * ez;
        }

        float4 wa, wb;
        wa.x = ox*k0[0] + oy*k1[0] + oz*k2[0];
        wa.y = ox*k0[1] + oy*k1[1] + oz*k2[1];
        wa.z = ox*k0[2] + oy*k1[2] + oz*k2[2];
        wa.w = ox*k0[3] + oy*k1[3] + oz*k2[3];
        wb.x = ox*k0[4] + oy*k1[4] + oz*k2[4];
        wb.y = ox*k0[5] + oy*k1[5] + oz*k2[5];
        wb.z = ox*k0[6] + oy*k1[6] + oz*k2[6];
        wb.w = ox*k0[7] + oy*k1[7] + oz*k2[7];

        float* orow = out + ybase + (size_t)row * LATENT + hl * 8;
        *(float4*)(orow)     = wa;
        *(float4*)(orow + 4) = wb;
    }
}

extern "C" void kernel_launch(void* const* d_in, const int* in_sizes, int n_in,
                              void* d_out, int out_size, void* d_ws, size_t ws_size,
                              hipStream_t stream) {
    // setup_inputs order: y[f32 N*256], z[f32 N] (unused), K[f32 256*6],
    // batch[int32 N] (unused — shape only).
    const float* y = (const float*)d_in[0];
    const float* K = (const float*)d_in[2];
    float* out = (float*)d_out;

    int N  = (n_in > 1 && in_sizes) ? in_sizes[1] : (1024 * NPEND);
    int nb = N / NPEND;
    if (nb <= 0) nb = 1024;
    (void)out_size; (void)d_ws; (void)ws_size;

    pend_kernel_f32<<<nb, 256, 0, stream>>>(y, K, out);
}

// Round 3
// 239.622 us; speedup vs baseline: 1.0361x; 1.0361x over previous
//
#include <hip/hip_runtime.h>

// Problem constants (fixed by the reference's setup_inputs)
#define NPEND  128
#define LATENT 256
#define KCOLS  6
#define D0_C   1.0f
#define SEG    32            // output rows per block
#define SEGS_PER_CHAIN (NPEND / SEG)   // 4

// One block per 32-row chain segment (+2 halo rows recomputed).
// Phase 1: r[row] = y[row,:] @ K[:, :3] for rows [row0-1, row0+SEG] into LDS.
// Phase 2: stencil + rank-3 expansion, write 32 output rows.
// Halo recompute removes all inter-block coupling -> grid 4096, full occupancy.
__global__ __launch_bounds__(256)
void pend_kernel_f32(const float* __restrict__ y,
                     const float* __restrict__ K,
                     float* __restrict__ out)
{
    __shared__ float sR[SEG + 2][3];

    const int tid  = threadIdx.x;
    const int hwid = tid >> 5;          // half-wave id 0..7
    const int hl   = tid & 31;          // lane within half-wave

    const int chain = blockIdx.x >> 2;  // SEGS_PER_CHAIN == 4
    const int seg   = blockIdx.x & 3;
    const int row0  = seg * SEG;
    const int rlo   = (row0 > 0) ? row0 - 1 : 0;
    const int rhi   = (row0 + SEG < NPEND) ? row0 + SEG : NPEND - 1; // inclusive
    const int nrows = rhi - rlo + 1;    // 33 or 34

    // This lane owns latent indices l = hl*8 + e (e = 0..7)
    float k0[8], k1[8], k2[8];
#pragma unroll
    for (int e = 0; e < 8; ++e) {
        const int l = hl * 8 + e;
        k0[e] = K[l * KCOLS + 0];
        k1[e] = K[l * KCOLS + 1];
        k2[e] = K[l * KCOLS + 2];
    }

    const size_t cbase = (size_t)chain * ((size_t)NPEND * LATENT);

    // ---- Phase 1: r rows [rlo, rhi] (each half-wave reduces one row) ----
    for (int i = hwid; i < nrows; i += 8) {
        const int row = rlo + i;
        const float* yr = y + cbase + (size_t)row * LATENT + hl * 8;
        const float4 va = *(const float4*)(yr);
        const float4 vb = *(const float4*)(yr + 4);

        float s0 = va.x*k0[0] + va.y*k0[1] + va.z*k0[2] + va.w*k0[3]
                 + vb.x*k0[4] + vb.y*k0[5] + vb.z*k0[6] + vb.w*k0[7];
        float s1 = va.x*k1[0] + va.y*k1[1] + va.z*k1[2] + va.w*k1[3]
                 + vb.x*k1[4] + vb.y*k1[5] + vb.z*k1[6] + vb.w*k1[7];
        float s2 = va.x*k2[0] + va.y*k2[1] + va.z*k2[2] + va.w*k2[3]
                 + vb.x*k2[4] + vb.y*k2[5] + vb.z*k2[6] + vb.w*k2[7];

#pragma unroll
        for (int off = 16; off > 0; off >>= 1) {
            s0 += __shfl_down(s0, off, 32);
            s1 += __shfl_down(s1, off, 32);
            s2 += __shfl_down(s2, off, 32);
        }
        if (hl == 0) {
            sR[i][0] = s0; sR[i][1] = s1; sR[i][2] = s2;
        }
    }
    __syncthreads();

    // ---- Phase 2: out3[row] = t(row) - t(row+1); expand by K[:, :3]^T ----
    for (int i = hwid; i < SEG; i += 8) {
        const int row = row0 + i;
        const int si  = row - rlo;      // index into sR

        const float rx = sR[si][0], ry = sR[si][1], rz = sR[si][2];
        float px = 0.f, py = 0.f, pz = 0.f;
        if (row > 0) { px = sR[si-1][0]; py = sR[si-1][1]; pz = sR[si-1][2]; }

        const float dx = rx - px, dy = ry - py, dz = rz - pz;
        const float n  = sqrtf(dx*dx + dy*dy + dz*dz);
        const float s  = (n - D0_C) / n;
        float ox = s * dx, oy = s * dy, oz = s * dz;

        if (row < NPEND - 1) {
            const float nx = sR[si+1][0], ny = sR[si+1][1], nz = sR[si+1][2];
            const float ex = nx - rx, ey = ny - ry, ez = nz - rz;
            const float n2 = sqrtf(ex*ex + ey*ey + ez*ez);
            const float t2 = (n2 - D0_C) / n2;
            ox -= t2 * ex; oy -= t2 * ey; oz -= t2 * ez;
        }

        float4 wa, wb;
        wa.x = ox*k0[0] + oy*k1[0] + oz*k2[0];
        wa.y = ox*k0[1] + oy*k1[1] + oz*k2[1];
        wa.z = ox*k0[2] + oy*k1[2] + oz*k2[2];
        wa.w = ox*k0[3] + oy*k1[3] + oz*k2[3];
        wb.x = ox*k0[4] + oy*k1[4] + oz*k2[4];
        wb.y = ox*k0[5] + oy*k1[5] + oz*k2[5];
        wb.z = ox*k0[6] + oy*k1[6] + oz*k2[6];
        wb.w = ox*k0[7] + oy*k1[7] + oz*k2[7];

        float* orow = out + cbase + (size_t)row * LATENT + hl * 8;
        *(float4*)(orow)     = wa;
        *(float4*)(orow + 4) = wb;
    }
}

extern "C" void kernel_launch(void* const* d_in, const int* in_sizes, int n_in,
                              void* d_out, int out_size, void* d_ws, size_t ws_size,
                              hipStream_t stream) {
    // setup_inputs order: y[f32 N*256], z[f32 N] (unused), K[f32 256*6],
    // batch[int32 N] (unused — shape only).
    const float* y = (const float*)d_in[0];
    const float* K = (const float*)d_in[2];
    float* out = (float*)d_out;

    int N  = (n_in > 1 && in_sizes) ? in_sizes[1] : (1024 * NPEND);
    int nb = N / NPEND;
    if (nb <= 0) nb = 1024;
    (void)out_size; (void)d_ws; (void)ws_size;

    pend_kernel_f32<<<nb * SEGS_PER_CHAIN, 256, 0, stream>>>(y, K, out);
}

// Round 4
// 238.871 us; speedup vs baseline: 1.0393x; 1.0031x over previous
//
#include <hip/hip_runtime.h>

// Problem constants (fixed by the reference's setup_inputs)
#define NPEND  128
#define LATENT 256
#define KCOLS  6
#define D0_C   1.0f
#define SEG    32                      // output rows per block
#define SEGS_PER_CHAIN (NPEND / SEG)   // 4
#define ROWS_PER_HALF 5                // ceil(34 / 8)

// One block per 32-row chain segment (+2 halo rows recomputed).
// Phase 1: each half-wave computes r for up to 5 rows. All 10 float4 loads
// are issued before any use (MLP); the 32-wide butterfly reduce runs 15
// independent chains (5 rows x 3 comps) so ds latency is hidden by ILP.
// Phase 2: stencil + rank-3 expansion (lane owns an 8-wide latent slice,
// K[:, :3] held in 24 registers), fully unrolled.
__global__ __launch_bounds__(256)
void pend_kernel_f32(const float* __restrict__ y,
                     const float* __restrict__ K,
                     float* __restrict__ out)
{
    __shared__ float sR[SEG + 2][3];

    const int tid  = threadIdx.x;
    const int hwid = tid >> 5;          // half-wave id 0..7
    const int hl   = tid & 31;          // lane within half-wave

    const int chain = blockIdx.x >> 2;  // SEGS_PER_CHAIN == 4
    const int seg   = blockIdx.x & 3;
    const int row0  = seg * SEG;
    const int rlo   = (row0 > 0) ? row0 - 1 : 0;
    const int rhi   = (row0 + SEG < NPEND) ? row0 + SEG : NPEND - 1; // inclusive
    const int nrows = rhi - rlo + 1;    // 33 or 34

    // This lane owns latent indices l = hl*8 + e (e = 0..7)
    float k0[8], k1[8], k2[8];
#pragma unroll
    for (int e = 0; e < 8; ++e) {
        const int l = hl * 8 + e;
        k0[e] = K[l * KCOLS + 0];
        k1[e] = K[l * KCOLS + 1];
        k2[e] = K[l * KCOLS + 2];
    }

    const size_t cbase = (size_t)chain * ((size_t)NPEND * LATENT);

    // ---- Phase 1: issue ALL loads first (10 float4 in flight per lane) ----
    float4 va[ROWS_PER_HALF], vb[ROWS_PER_HALF];
#pragma unroll
    for (int j = 0; j < ROWS_PER_HALF; ++j) {
        int i = hwid + 8 * j;
        int row = rlo + ((i < nrows) ? i : (nrows - 1));  // clamp: harmless dup
        const float* yr = y + cbase + (size_t)row * LATENT + hl * 8;
        va[j] = *(const float4*)(yr);
        vb[j] = *(const float4*)(yr + 4);
    }

    // Per-row partial dot products (24 FMAs per row per lane)
    float s0[ROWS_PER_HALF], s1[ROWS_PER_HALF], s2[ROWS_PER_HALF];
#pragma unroll
    for (int j = 0; j < ROWS_PER_HALF; ++j) {
        s0[j] = va[j].x*k0[0] + va[j].y*k0[1] + va[j].z*k0[2] + va[j].w*k0[3]
              + vb[j].x*k0[4] + vb[j].y*k0[5] + vb[j].z*k0[6] + vb[j].w*k0[7];
        s1[j] = va[j].x*k1[0] + va[j].y*k1[1] + va[j].z*k1[2] + va[j].w*k1[3]
              + vb[j].x*k1[4] + vb[j].y*k1[5] + vb[j].z*k1[6] + vb[j].w*k1[7];
        s2[j] = va[j].x*k2[0] + va[j].y*k2[1] + va[j].z*k2[2] + va[j].w*k2[3]
              + vb[j].x*k2[4] + vb[j].y*k2[5] + vb[j].z*k2[6] + vb[j].w*k2[7];
    }

    // 32-wide butterfly reduce: 5 rounds x 15 independent chains
#pragma unroll
    for (int off = 16; off > 0; off >>= 1) {
#pragma unroll
        for (int j = 0; j < ROWS_PER_HALF; ++j) {
            s0[j] += __shfl_down(s0[j], off, 32);
            s1[j] += __shfl_down(s1[j], off, 32);
            s2[j] += __shfl_down(s2[j], off, 32);
        }
    }
    if (hl == 0) {
#pragma unroll
        for (int j = 0; j < ROWS_PER_HALF; ++j) {
            int i = hwid + 8 * j;
            if (i < nrows) {
                sR[i][0] = s0[j]; sR[i][1] = s1[j]; sR[i][2] = s2[j];
            }
        }
    }
    __syncthreads();

    // ---- Phase 2: out3[row] = t(row) - t(row+1); expand by K[:, :3]^T ----
#pragma unroll
    for (int j = 0; j < SEG / 8; ++j) {
        const int i   = hwid + 8 * j;
        const int row = row0 + i;
        const int si  = row - rlo;      // index into sR

        const float rx = sR[si][0], ry = sR[si][1], rz = sR[si][2];
        float px = 0.f, py = 0.f, pz = 0.f;
        if (row > 0) { px = sR[si-1][0]; py = sR[si-1][1]; pz = sR[si-1][2]; }

        const float dx = rx - px, dy = ry - py, dz = rz - pz;
        const float n  = sqrtf(dx*dx + dy*dy + dz*dz);
        const float s  = (n - D0_C) / n;
        float ox = s * dx, oy = s * dy, oz = s * dz;

        if (row < NPEND - 1) {
            const float nx = sR[si+1][0], ny = sR[si+1][1], nz = sR[si+1][2];
            const float ex = nx - rx, ey = ny - ry, ez = nz - rz;
            const float n2 = sqrtf(ex*ex + ey*ey + ez*ez);
            const float t2 = (n2 - D0_C) / n2;
            ox -= t2 * ex; oy -= t2 * ey; oz -= t2 * ez;
        }

        float4 wa, wb;
        wa.x = ox*k0[0] + oy*k1[0] + oz*k2[0];
        wa.y = ox*k0[1] + oy*k1[1] + oz*k2[1];
        wa.z = ox*k0[2] + oy*k1[2] + oz*k2[2];
        wa.w = ox*k0[3] + oy*k1[3] + oz*k2[3];
        wb.x = ox*k0[4] + oy*k1[4] + oz*k2[4];
        wb.y = ox*k0[5] + oy*k1[5] + oz*k2[5];
        wb.z = ox*k0[6] + oy*k1[6] + oz*k2[6];
        wb.w = ox*k0[7] + oy*k1[7] + oz*k2[7];

        float* orow = out + cbase + (size_t)row * LATENT + hl * 8;
        *(float4*)(orow)     = wa;
        *(float4*)(orow + 4) = wb;
    }
}

extern "C" void kernel_launch(void* const* d_in, const int* in_sizes, int n_in,
                              void* d_out, int out_size, void* d_ws, size_t ws_size,
                              hipStream_t stream) {
    // setup_inputs order: y[f32 N*256], z[f32 N] (unused), K[f32 256*6],
    // batch[int32 N] (unused — shape only).
    const float* y = (const float*)d_in[0];
    const float* K = (const float*)d_in[2];
    float* out = (float*)d_out;

    int N  = (n_in > 1 && in_sizes) ? in_sizes[1] : (1024 * NPEND);
    int nb = N / NPEND;
    if (nb <= 0) nb = 1024;
    (void)out_size; (void)d_ws; (void)ws_size;

    pend_kernel_f32<<<nb * SEGS_PER_CHAIN, 256, 0, stream>>>(y, K, out);
}